// Round 15
// baseline (2555.759 us; speedup 1.0000x reference)
//
#include <hip/hip_runtime.h>
#include <hip/hip_cooperative_groups.h>
#include <math.h>

namespace cg = cooperative_groups;

// ---------------------------------------------------------------------------
// LinSinkhornPRModel: sigmoid(dist2 - dist1) of two Sinkhorn divergences.
//   - f_aa self-term cancels in dist2-dist1 -> C_xx never built.
//   - R13: single cost launch, fp16 C+CT, uniform row-only rounds (272us).
//   - R14 FAIL post-mortem: cooperative launch at 2048 blocks = equality-
//     tight residency (needs exactly 8/CU at 64 VGPR) -> silent launch fail.
//   - R15: cooperative grid 1024 (2 tiles/block, bounds(256,4): residency
//     margin 2x) + checked launch with deterministic R13 fallback.
// ---------------------------------------------------------------------------

typedef __attribute__((ext_vector_type(8))) short short8;
typedef __attribute__((ext_vector_type(4))) float f32x4;
typedef __attribute__((ext_vector_type(8))) unsigned short u16x8;
typedef __attribute__((ext_vector_type(4))) unsigned short u16x4;

#define LOG2E 1.4426950408889634
#define LN2   0.6931471805599453
#define NROUNDS 13

__device__ __forceinline__ float exp2fast(float x){
#if __has_builtin(__builtin_amdgcn_exp2f)
    return __builtin_amdgcn_exp2f(x);
#else
    return exp2f(x);
#endif
}
__device__ __forceinline__ void lse2_merge(float& m, float& s, float mo, float so){
    float M2 = fmaxf(m, mo);
    s = s * exp2fast(m - M2) + so * exp2fast(mo - M2);
    m = M2;
}
__device__ __forceinline__ unsigned short f2bf(float x){
    unsigned u = __float_as_uint(x);
    unsigned r = u + 0x7fffu + ((u >> 16) & 1u);
    return (unsigned short)(r >> 16);
}
__device__ __forceinline__ float h2f(unsigned short u){
    _Float16 h; __builtin_memcpy(&h, &u, 2); return (float)h;
}
__device__ __forceinline__ unsigned short f2h(float f){
    _Float16 h = (_Float16)f; unsigned short u; __builtin_memcpy(&u, &h, 2); return u;
}
__device__ __forceinline__ float max8(const float* v){
    return fmaxf(fmaxf(fmaxf(v[0], v[1]), fmaxf(v[2], v[3])),
                 fmaxf(fmaxf(v[4], v[5]), fmaxf(v[6], v[7])));
}

// ----------------------------- setup kernels -------------------------------

__global__ __launch_bounds__(256)
void k_setup(const float* __restrict__ W, float* __restrict__ WT,
             const float* __restrict__ h, const float* __restrict__ hi,
             const float* __restrict__ hj, float* __restrict__ lg)
{
    const int b = blockIdx.x, t = threadIdx.x;
    if (b < 64) {
        int bb = b * 2 + (t >> 7), tt = t & 127;
        WT[bb * 128 + tt] = W[tt * 128 + bb];
        return;
    }
    int i = (b - 64) * 256 + t;   // 8192 total
    float x;
    if (i < 4096)      x = h[i];
    else if (i < 6144) x = hi[i - 4096];
    else               x = hj[i - 6144];
    lg[i] = __log2f(x);
}

__global__ __launch_bounds__(128)
void k_transform_all(const float* __restrict__ d, const float* __restrict__ si,
                     const float* __restrict__ sj, const float* __restrict__ WT,
                     unsigned short* __restrict__ th, float* __restrict__ hn)
{
    __shared__ float xs[8][128];
    __shared__ float red[16];
    const int t = threadIdx.x;
    const int r0 = blockIdx.x * 8;
    const float* src; int sr;
    if (r0 < 4096)      { src = d;  sr = r0; }
    else if (r0 < 6144) { src = si; sr = r0 - 4096; }
    else                { src = sj; sr = r0 - 6144; }
    for (int rr = 0; rr < 8; ++rr)
        xs[rr][t] = src[(size_t)(sr + rr) * 128 + t];
    __syncthreads();
    float acc[8];
#pragma unroll
    for (int rr = 0; rr < 8; ++rr) acc[rr] = 0.f;
    for (int k = 0; k < 128; ++k) {
        float wv = WT[k * 128 + t];
#pragma unroll
        for (int rr = 0; rr < 8; ++rr) acc[rr] = fmaf(xs[rr][k], wv, acc[rr]);
    }
#pragma unroll
    for (int rr = 0; rr < 8; ++rr) {
        float a = acc[rr];
        th[(size_t)(r0 + rr) * 128 + t] = f2bf(a);
        float sq = a * a;
#pragma unroll
        for (int o = 1; o < 64; o <<= 1) sq += __shfl_xor(sq, o);
        if ((t & 63) == 0) red[(t >> 6) * 8 + rr] = sq;
    }
    __syncthreads();
    if (t < 8) hn[r0 + t] = 0.5f * (red[t] + red[8 + t]);
}

// ------------------------------ cost GEMM (MFMA) ---------------------------
struct CostPair {
    const unsigned short *Ah, *Bh;
    const float *hna, *hnb;
    unsigned short* C; unsigned short* CT;   // CT may be null
    int ldc; int ldct;
    int blk0; int nbx;
};
struct CostQuad { CostPair p[4]; };

#define CPAD 136

__global__ __launch_bounds__(256)
void k_cost_mfma(CostQuad Q)
{
    const int b = blockIdx.x;
    CostPair P = Q.p[3];
    if      (b < Q.p[1].blk0) P = Q.p[0];
    else if (b < Q.p[2].blk0) P = Q.p[1];
    else if (b < Q.p[3].blk0) P = Q.p[2];
    const int bl = b - P.blk0;
    const int i0 = (bl / P.nbx) * 64, j0 = (bl % P.nbx) * 128;
    const int w = threadIdx.x >> 6, lane = threadIdx.x & 63;
    const int rh = w >> 1, ch = w & 1;
    const int ar = i0 + rh * 32;
    const int bc = j0 + ch * 64;
    const int lrow = lane & 15;
    const int kgrp = (lane >> 4) * 8;

    __shared__ unsigned short lds_c[64][CPAD];

    f32x4 acc[2][4];
#pragma unroll
    for (int a = 0; a < 2; ++a)
#pragma unroll
        for (int c = 0; c < 4; ++c) acc[a][c] = (f32x4){0.f, 0.f, 0.f, 0.f};

    short8 ah[2][4], bh[4][4];
#pragma unroll
    for (int kc = 0; kc < 4; ++kc) {
#pragma unroll
        for (int f = 0; f < 2; ++f)
            ah[f][kc] = *reinterpret_cast<const short8*>(
                P.Ah + (size_t)(ar + f * 16 + lrow) * 128 + kc * 32 + kgrp);
#pragma unroll
        for (int f = 0; f < 4; ++f)
            bh[f][kc] = *reinterpret_cast<const short8*>(
                P.Bh + (size_t)(bc + f * 16 + lrow) * 128 + kc * 32 + kgrp);
    }
#pragma unroll
    for (int kc = 0; kc < 4; ++kc)
#pragma unroll
        for (int fi = 0; fi < 2; ++fi)
#pragma unroll
            for (int fj = 0; fj < 4; ++fj)
                acc[fi][fj] = __builtin_amdgcn_mfma_f32_16x16x32_bf16(
                    bh[fj][kc], ah[fi][kc], acc[fi][fj], 0, 0, 0);

    const int rloc = lane & 15, cloc = (lane >> 4) * 4;
#pragma unroll
    for (int fi = 0; fi < 2; ++fi) {
        int lr = rh * 32 + fi * 16 + rloc;
        float ha = P.hna[i0 + lr];
#pragma unroll
        for (int fj = 0; fj < 4; ++fj) {
            int lc = ch * 64 + fj * 16 + cloc;
            f32x4 hb = *reinterpret_cast<const f32x4*>(P.hnb + j0 + lc);
            u16x4 v;
#pragma unroll
            for (int e = 0; e < 4; ++e)
                v[e] = f2h(fmaxf(ha + hb[e] - acc[fi][fj][e], 0.f));
            *reinterpret_cast<u16x4*>(&lds_c[lr][lc]) = v;
        }
    }
    __syncthreads();
    {
        const int row = threadIdx.x >> 2, q = threadIdx.x & 3;
        const unsigned short* srcp = &lds_c[row][q * 32];
        unsigned short* dstp = P.C + (size_t)(i0 + row) * P.ldc + j0 + q * 32;
#pragma unroll
        for (int k = 0; k < 4; ++k)
            *reinterpret_cast<u16x8*>(dstp + 8 * k) =
                *reinterpret_cast<const u16x8*>(srcp + 8 * k);
    }
    if (P.CT) {
        const int tr = threadIdx.x >> 1, half = threadIdx.x & 1;
        unsigned short* dstp = P.CT + (size_t)(j0 + tr) * P.ldct + i0 + half * 32;
#pragma unroll
        for (int k = 0; k < 4; ++k) {
            u16x8 v;
#pragma unroll
            for (int e = 0; e < 8; ++e)
                v[e] = lds_c[half * 32 + k * 8 + e][tr];
            *reinterpret_cast<u16x8*>(dstp + 8 * k) = v;
        }
    }
}

// ------------------------ shared round machinery ---------------------------

struct RT7 {
    const unsigned short* C;
    const float* Win;
    const float* fold; const float* logself;
    float* vout; float* wout;
    int blk0; int wide;
};
struct R7Args {
    RT7 t[6];
    float ie2, epsln2, ie2n, alpha, beta;
};

// One 8-row tile pass: writes per-thread partials into lmS/lsS, then the
// caller-side reduce finalizes. Used by both fallback and fused kernels.
__device__ __forceinline__ void tile_pass(
    const unsigned short* C, const float* Win, const float* fold,
    const float* logself, float* vout, float* wout,
    int row0, int wide, float nie2, float epsln2, float ie2n,
    float alpha, float beta, int tid,
    float (*lmS)[256], float (*lsS)[256])
{
    if (!wide) {
        const int c0 = tid * 8;
        float wb[8];
#pragma unroll
        for (int e = 0; e < 8; ++e) wb[e] = Win[c0 + e];
#pragma unroll
        for (int rr = 0; rr < 8; ++rr) {
            u16x8 c = *reinterpret_cast<const u16x8*>(C + (size_t)(row0 + rr) * 2048 + c0);
            float v[8];
#pragma unroll
            for (int e = 0; e < 8; ++e) v[e] = fmaf(h2f(c[e]), nie2, wb[e]);
            float M8 = max8(v);
            float s8 = 0.f;
#pragma unroll
            for (int e = 0; e < 8; ++e) s8 += exp2fast(v[e] - M8);
            lmS[rr][tid] = M8; lsS[rr][tid] = s8;
        }
    } else {
        const int c0 = tid * 16;
        float wb[16];
#pragma unroll
        for (int e = 0; e < 16; ++e) wb[e] = Win[c0 + e];
#pragma unroll
        for (int rr = 0; rr < 8; ++rr) {
            const unsigned short* Cr = C + (size_t)(row0 + rr) * 4096 + c0;
            u16x8 ca = *reinterpret_cast<const u16x8*>(Cr);
            u16x8 cb = *reinterpret_cast<const u16x8*>(Cr + 8);
            float v[16];
#pragma unroll
            for (int e = 0; e < 8; ++e) {
                v[e]     = fmaf(h2f(ca[e]), nie2, wb[e]);
                v[8 + e] = fmaf(h2f(cb[e]), nie2, wb[8 + e]);
            }
            float M = fmaxf(max8(v), max8(v + 8));
            float s = 0.f;
#pragma unroll
            for (int e = 0; e < 16; ++e) s += exp2fast(v[e] - M);
            lmS[rr][tid] = M; lsS[rr][tid] = s;
        }
    }
    __syncthreads();
    {
        const int row = tid >> 5, g = tid & 31;
        float m = lmS[row][g], s = lsS[row][g];
#pragma unroll
        for (int k = 1; k < 8; ++k)
            lse2_merge(m, s, lmS[row][g + 32 * k], lsS[row][g + 32 * k]);
#pragma unroll
        for (int oo = 1; oo < 32; oo <<= 1) {
            float mo = __shfl_xor(m, oo), so = __shfl_xor(s, oo);
            lse2_merge(m, s, mo, so);
        }
        if (g == 0) {
            int rr = row0 + row;
            float val  = -epsln2 * (m + __log2f(s));
            float vnew = alpha * fold[rr] + beta * val;
            vout[rr] = vnew;
            wout[rr] = fmaf(vnew, ie2n, logself[rr]);
        }
    }
    __syncthreads();
}

// --------------------- fallback per-round kernel (R13) ---------------------

__global__ __launch_bounds__(256, 8)
void k_round7(R7Args A)
{
    __shared__ float lmS[8][256];
    __shared__ float lsS[8][256];
    const int b = blockIdx.x;
    int ti = 5;
    if      (b < A.t[1].blk0) ti = 0;
    else if (b < A.t[2].blk0) ti = 1;
    else if (b < A.t[3].blk0) ti = 2;
    else if (b < A.t[4].blk0) ti = 3;
    else if (b < A.t[5].blk0) ti = 4;
    RT7 T = A.t[ti];
    tile_pass(T.C, T.Win, T.fold, T.logself, T.vout, T.wout,
              (b - T.blk0) * 8, T.wide, -A.ie2, A.epsln2, A.ie2n,
              A.alpha, A.beta, threadIdx.x, lmS, lsS);
}

__global__ __launch_bounds__(1024)
void k_final(const float* __restrict__ h, const float* __restrict__ hi,
             const float* __restrict__ hj,
             const float* __restrict__ f1f, const float* __restrict__ f2f,
             const float* __restrict__ g1f, const float* __restrict__ gb1f,
             const float* __restrict__ g2f, const float* __restrict__ gb2f,
             int N, int M, float* __restrict__ out)
{
    float acc = 0.f;
    for (int i = threadIdx.x; i < N; i += 1024)
        acc += h[i] * (f2f[i] - f1f[i]);
    for (int j = threadIdx.x; j < M; j += 1024)
        acc += hj[j] * (g2f[j] - gb2f[j]) - hi[j] * (g1f[j] - gb1f[j]);
#pragma unroll
    for (int o = 32; o; o >>= 1) acc += __shfl_xor(acc, o);
    __shared__ float red[16];
    const int lane = threadIdx.x & 63, w = threadIdx.x >> 6;
    if (lane == 0) red[w] = acc;
    __syncthreads();
    if (threadIdx.x == 0) {
        float t = 0.f;
        for (int q = 0; q < 16; ++q) t += red[q];
        out[0] = 1.f / (1.f + expf(-t));   // SCALING_FACTOR = 1
    }
}

// ----------------------- fused rounds (cooperative) ------------------------
// 1024 blocks x 256 threads, 2 tiles/block/round (4 blocks/CU residency,
// margin >= 2x). grid.sync + threadfence between rounds.

struct FusedArgs {
    const unsigned short* cm[6];
    const float* winit[6];
    const float* lself[6];
    float* vbuf[6][2];
    float* vfin[6];
    float* winb[6][2];
    float* woutb[6][2];
    const float* h; const float* hi; const float* hj;
    float* out;
    float ie2[NROUNDS], epsln2[NROUNDS], ie2n[NROUNDS];
};

__global__ __launch_bounds__(256, 4)
void k_rounds_fused(FusedArgs A)
{
    cg::grid_group grid = cg::this_grid();
    __shared__ float lmS[8][256];
    __shared__ float lsS[8][256];
    const int tid = threadIdx.x;
    const int blk0arr[6] = { 0, 512, 1024, 1280, 1536, 1792 };

    for (int r = 0; r < NROUNDS; ++r) {
        const bool init = (r == 0), fin = (r == NROUNDS - 1);
        const int in = init ? 0 : (r - 1) & 1;
        const int o  = r & 1;
        const float nie2  = -A.ie2[r];
        const float alpha = (init || fin) ? 0.f : 0.5f;
        const float beta  = (init || fin) ? 1.f : 0.5f;
#pragma unroll
        for (int half = 0; half < 2; ++half) {
            const int bb = blockIdx.x + half * 1024;
            int ti = 5;
            if      (bb <  512) ti = 0;
            else if (bb < 1024) ti = 1;
            else if (bb < 1280) ti = 2;
            else if (bb < 1536) ti = 3;
            else if (bb < 1792) ti = 4;
            const int row0 = (bb - blk0arr[ti]) * 8;
            const bool wide = (ti == 2 || ti == 3);
            const float* Win  = init ? A.winit[ti] : A.winb[ti][in];
            tile_pass(A.cm[ti], Win, A.vbuf[ti][in], A.lself[ti],
                      fin ? A.vfin[ti] : A.vbuf[ti][o], A.woutb[ti][o],
                      row0, wide, nie2, A.epsln2[r], A.ie2n[r],
                      alpha, beta, tid, lmS, lsS);
        }
        __threadfence();
        grid.sync();
    }

    if (blockIdx.x == 0) {
        float acc = 0.f;
        for (int i = tid; i < 4096; i += 256)
            acc += A.h[i] * (A.vfin[1][i] - A.vfin[0][i]);
        for (int j = tid; j < 2048; j += 256)
            acc += A.hj[j] * (A.vfin[3][j] - A.vfin[5][j])
                 - A.hi[j] * (A.vfin[2][j] - A.vfin[4][j]);
#pragma unroll
        for (int oo = 32; oo; oo >>= 1) acc += __shfl_xor(acc, oo);
        __shared__ float red[4];
        const int lane = tid & 63, w = tid >> 6;
        if (lane == 0) red[w] = acc;
        __syncthreads();
        if (tid == 0) {
            float t = red[0] + red[1] + red[2] + red[3];
            A.out[0] = 1.f / (1.f + expf(-t));   // SCALING_FACTOR = 1
        }
    }
}

// ------------------------------ orchestration ------------------------------

extern "C" void kernel_launch(void* const* d_in, const int* in_sizes, int n_in,
                              void* d_out, int out_size, void* d_ws, size_t ws_size,
                              hipStream_t stream)
{
    const float* d  = (const float*)d_in[0];
    const float* si = (const float*)d_in[1];
    const float* sj = (const float*)d_in[2];
    const float* h  = (const float*)d_in[3];
    const float* hi = (const float*)d_in[4];
    const float* hj = (const float*)d_in[5];
    const float* W  = (const float*)d_in[6];
    float* out = (float*)d_out;

    const int N = 4096, M = 2048;
    (void)in_sizes; (void)n_in; (void)out_size; (void)ws_size;

    float* ws = (float*)d_ws;
    size_t off = 0;
    auto alloc = [&](size_t n) { float* p = ws + off; off += (n + 63) & ~(size_t)63; return p; };

    float* WT    = alloc(128 * 128);
    float* lg2   = alloc(8192);
    float* hnAll = alloc(8192);
    unsigned short* thAll = (unsigned short*)alloc(8192 * 128 / 2);
    float* f1[2]  = { alloc(N), alloc(N) };
    float* f2[2]  = { alloc(N), alloc(N) };
    float* g1[2]  = { alloc(M), alloc(M) };
    float* g2[2]  = { alloc(M), alloc(M) };
    float* gb1[2] = { alloc(M), alloc(M) };
    float* gb2[2] = { alloc(M), alloc(M) };
    float* WA1[2] = { alloc(N), alloc(N) };
    float* WA2[2] = { alloc(N), alloc(N) };
    float* WB1[2] = { alloc(M), alloc(M) };
    float* WB2[2] = { alloc(M), alloc(M) };
    float* WY1[2] = { alloc(M), alloc(M) };
    float* WY2[2] = { alloc(M), alloc(M) };
    float* f1f = alloc(N); float* f2f = alloc(N);
    float* g1f = alloc(M); float* g2f = alloc(M);
    float* gb1f = alloc(M); float* gb2f = alloc(M);
    unsigned short* C1  = (unsigned short*)alloc((size_t)N * M / 2);
    unsigned short* C2  = (unsigned short*)alloc((size_t)N * M / 2);
    unsigned short* CT1 = (unsigned short*)alloc((size_t)M * N / 2);
    unsigned short* CT2 = (unsigned short*)alloc((size_t)M * N / 2);
    unsigned short* Cy1 = (unsigned short*)alloc((size_t)M * M / 2);
    unsigned short* Cy2 = (unsigned short*)alloc((size_t)M * M / 2);

    float* la2  = lg2;
    float* lbi2 = lg2 + 4096;
    float* lbj2 = lg2 + 6144;
    const float* hnx = hnAll;
    const float* hni = hnAll + 4096;
    const float* hnj = hnAll + 6144;
    const unsigned short* tdh  = thAll;
    const unsigned short* tsih = thAll + (size_t)4096 * 128;
    const unsigned short* tsjh = thAll + (size_t)6144 * 128;

    // ---- setup ----
    k_setup<<<96, 256, 0, stream>>>(W, WT, h, hi, hj, lg2);
    k_transform_all<<<1024, 128, 0, stream>>>(d, si, sj, WT, thAll, hnAll);

    // ---- cost matrices (+ CT for xy): one launch, 2560 blocks ----
    CostQuad Q;
    Q.p[0] = { tdh,  tsih, hnx, hni, C1,  CT1,     M, N,    0, 16 };
    Q.p[1] = { tdh,  tsjh, hnx, hnj, C2,  CT2,     M, N, 1024, 16 };
    Q.p[2] = { tsih, tsih, hni, hni, Cy1, nullptr, M, 0, 2048, 16 };
    Q.p[3] = { tsjh, tsjh, hnj, hnj, Cy2, nullptr, M, 0, 2304, 16 };
    k_cost_mfma<<<2560, 256, 0, stream>>>(Q);

    // ---- eps schedule -> per-round constants ----
    double epsl[16]; int ne = 0;
    for (double sg = 32.0; sg > 0.05; sg *= 0.5) epsl[ne++] = sg * sg;
    epsl[ne++] = 0.05 * 0.05;   // ne == 11; NROUNDS = ne + 2 = 13

    FusedArgs FA;
    for (int r = 0; r < NROUNDS; ++r) {
        const bool init = (r == 0), fin = (r == NROUNDS - 1);
        const double eps  = init ? epsl[0] : (fin ? epsl[ne - 1] : epsl[r - 1]);
        const double epsn = (r + 1 <= ne) ? epsl[r] : epsl[ne - 1];
        FA.ie2[r]    = (float)(LOG2E / eps);
        FA.epsln2[r] = (float)(eps * LN2);
        FA.ie2n[r]   = (float)(LOG2E / epsn);
    }
    const unsigned short* cms[6] = { C1, C2, CT1, CT2, Cy1, Cy2 };
    const float* winits[6] = { lbi2, lbj2, la2, la2, lbi2, lbj2 };
    const float* lselfs[6] = { la2, la2, lbi2, lbj2, lbi2, lbj2 };
    float* vfins[6] = { f1f, f2f, g1f, g2f, gb1f, gb2f };
    for (int k = 0; k < 6; ++k) {
        FA.cm[k] = cms[k]; FA.winit[k] = winits[k];
        FA.lself[k] = lselfs[k]; FA.vfin[k] = vfins[k];
    }
    for (int p = 0; p < 2; ++p) {
        float* vb[6]  = { f1[p], f2[p], g1[p], g2[p], gb1[p], gb2[p] };
        float* wi[6]  = { WB1[p], WB2[p], WA1[p], WA2[p], WY1[p], WY2[p] };
        float* wo[6]  = { WA1[p], WA2[p], WB1[p], WB2[p], WY1[p], WY2[p] };
        for (int k = 0; k < 6; ++k) {
            FA.vbuf[k][p] = vb[k]; FA.winb[k][p] = wi[k]; FA.woutb[k][p] = wo[k];
        }
    }
    FA.h = h; FA.hi = hi; FA.hj = hj; FA.out = out;

    void* kp[] = { &FA };
    hipError_t cerr = hipLaunchCooperativeKernel((const void*)k_rounds_fused,
                                                 dim3(1024), dim3(256), kp, 0, stream);
    if (cerr != hipSuccess) {
        // ---- deterministic fallback: R13 multi-launch path ----
        for (int r = 0; r < NROUNDS; ++r) {
            const bool init = (r == 0), fin = (r == NROUNDS - 1);
            const int in = init ? 0 : (r - 1) & 1;
            const int o  = r & 1;
            R7Args A;
            A.ie2 = FA.ie2[r]; A.epsln2 = FA.epsln2[r]; A.ie2n = FA.ie2n[r];
            A.alpha = (init || fin) ? 0.0f : 0.5f;
            A.beta  = (init || fin) ? 1.0f : 0.5f;
            A.t[0] = { C1,  init ? lbi2 : WB1[in], f1[in],  la2,
                       fin ? f1f  : f1[o],  WA1[o],    0, 0 };
            A.t[1] = { C2,  init ? lbj2 : WB2[in], f2[in],  la2,
                       fin ? f2f  : f2[o],  WA2[o],  512, 0 };
            A.t[2] = { CT1, init ? la2  : WA1[in], g1[in],  lbi2,
                       fin ? g1f  : g1[o],  WB1[o], 1024, 1 };
            A.t[3] = { CT2, init ? la2  : WA2[in], g2[in],  lbj2,
                       fin ? g2f  : g2[o],  WB2[o], 1280, 1 };
            A.t[4] = { Cy1, init ? lbi2 : WY1[in], gb1[in], lbi2,
                       fin ? gb1f : gb1[o], WY1[o], 1536, 0 };
            A.t[5] = { Cy2, init ? lbj2 : WY2[in], gb2[in], lbj2,
                       fin ? gb2f : gb2[o], WY2[o], 1792, 0 };
            k_round7<<<2048, 256, 0, stream>>>(A);
        }
        k_final<<<1, 1024, 0, stream>>>(h, hi, hj, f1f, f2f, g1f, gb1f, g2f,
                                        gb2f, N, M, out);
    }
}

// Round 16
// 272.894 us; speedup vs baseline: 9.3654x; 9.3654x over previous
//
#include <hip/hip_runtime.h>
#include <math.h>

// ---------------------------------------------------------------------------
// LinSinkhornPRModel: sigmoid(dist2 - dist1) of two Sinkhorn divergences.
//   - f_aa self-term cancels in dist2-dist1 -> C_xx never built.
//   - R13 (final structure): fp16 C + CT materialized by one MFMA cost
//     launch; 13 uniform row-only softmin rounds (1 launch each); final
//     weighted reduce. 272us measured.
//   - R14/R15 post-mortem: cooperative fusion of the rounds ran 10x SLOWER
//     (FETCH 540MB@217GB/s -- persistent blocks break the inter-round L3
//     residency sweep; 13 grid.syncs across 8 XCDs). Reverted for good.
// ---------------------------------------------------------------------------

typedef __attribute__((ext_vector_type(8))) short short8;
typedef __attribute__((ext_vector_type(4))) float f32x4;
typedef __attribute__((ext_vector_type(8))) unsigned short u16x8;
typedef __attribute__((ext_vector_type(4))) unsigned short u16x4;

#define LOG2E 1.4426950408889634
#define LN2   0.6931471805599453

__device__ __forceinline__ float exp2fast(float x){
#if __has_builtin(__builtin_amdgcn_exp2f)
    return __builtin_amdgcn_exp2f(x);
#else
    return exp2f(x);
#endif
}
__device__ __forceinline__ void lse2_merge(float& m, float& s, float mo, float so){
    float M2 = fmaxf(m, mo);
    s = s * exp2fast(m - M2) + so * exp2fast(mo - M2);
    m = M2;
}
__device__ __forceinline__ unsigned short f2bf(float x){
    unsigned u = __float_as_uint(x);
    unsigned r = u + 0x7fffu + ((u >> 16) & 1u);
    return (unsigned short)(r >> 16);
}
__device__ __forceinline__ float h2f(unsigned short u){
    _Float16 h; __builtin_memcpy(&h, &u, 2); return (float)h;
}
__device__ __forceinline__ unsigned short f2h(float f){
    _Float16 h = (_Float16)f; unsigned short u; __builtin_memcpy(&u, &h, 2); return u;
}
__device__ __forceinline__ float max8(const float* v){
    return fmaxf(fmaxf(fmaxf(v[0], v[1]), fmaxf(v[2], v[3])),
                 fmaxf(fmaxf(v[4], v[5]), fmaxf(v[6], v[7])));
}

// ----------------------------- setup kernels -------------------------------

// blocks 0-63: WT[k][o] = W[o][k];  blocks 64-95: lg = log2(prob vectors)
__global__ __launch_bounds__(256)
void k_setup(const float* __restrict__ W, float* __restrict__ WT,
             const float* __restrict__ h, const float* __restrict__ hi,
             const float* __restrict__ hj, float* __restrict__ lg)
{
    const int b = blockIdx.x, t = threadIdx.x;
    if (b < 64) {
        int bb = b * 2 + (t >> 7), tt = t & 127;
        WT[bb * 128 + tt] = W[tt * 128 + bb];
        return;
    }
    int i = (b - 64) * 256 + t;   // 8192 total
    float x;
    if (i < 4096)      x = h[i];
    else if (i < 6144) x = hi[i - 4096];
    else               x = hj[i - 6144];
    lg[i] = __log2f(x);
}

__global__ __launch_bounds__(128)
void k_transform_all(const float* __restrict__ d, const float* __restrict__ si,
                     const float* __restrict__ sj, const float* __restrict__ WT,
                     unsigned short* __restrict__ th, float* __restrict__ hn)
{
    __shared__ float xs[8][128];
    __shared__ float red[16];
    const int t = threadIdx.x;
    const int r0 = blockIdx.x * 8;
    const float* src; int sr;
    if (r0 < 4096)      { src = d;  sr = r0; }
    else if (r0 < 6144) { src = si; sr = r0 - 4096; }
    else                { src = sj; sr = r0 - 6144; }
    for (int rr = 0; rr < 8; ++rr)
        xs[rr][t] = src[(size_t)(sr + rr) * 128 + t];
    __syncthreads();
    float acc[8];
#pragma unroll
    for (int rr = 0; rr < 8; ++rr) acc[rr] = 0.f;
    for (int k = 0; k < 128; ++k) {
        float wv = WT[k * 128 + t];
#pragma unroll
        for (int rr = 0; rr < 8; ++rr) acc[rr] = fmaf(xs[rr][k], wv, acc[rr]);
    }
#pragma unroll
    for (int rr = 0; rr < 8; ++rr) {
        float a = acc[rr];
        th[(size_t)(r0 + rr) * 128 + t] = f2bf(a);
        float sq = a * a;
#pragma unroll
        for (int o = 1; o < 64; o <<= 1) sq += __shfl_xor(sq, o);
        if ((t & 63) == 0) red[(t >> 6) * 8 + rr] = sq;
    }
    __syncthreads();
    if (t < 8) hn[r0 + t] = 0.5f * (red[t] + red[8 + t]);
}

// ------------------------------ cost GEMM (MFMA) ---------------------------
// C[i][j] = max(hna[i]+hnb[j]-dot, 0) fp16, single bf16 pass; optionally
// also writes CT[j][i]. All 4 matrices in one launch, linear block ranges.
struct CostPair {
    const unsigned short *Ah, *Bh;
    const float *hna, *hnb;
    unsigned short* C; unsigned short* CT;   // CT may be null
    int ldc; int ldct;
    int blk0; int nbx;                        // linear range start, x-blocks
};
struct CostQuad { CostPair p[4]; };

#define CPAD 136

__global__ __launch_bounds__(256)
void k_cost_mfma(CostQuad Q)
{
    const int b = blockIdx.x;
    CostPair P = Q.p[3];
    if      (b < Q.p[1].blk0) P = Q.p[0];
    else if (b < Q.p[2].blk0) P = Q.p[1];
    else if (b < Q.p[3].blk0) P = Q.p[2];
    const int bl = b - P.blk0;
    const int i0 = (bl / P.nbx) * 64, j0 = (bl % P.nbx) * 128;
    const int w = threadIdx.x >> 6, lane = threadIdx.x & 63;
    const int rh = w >> 1, ch = w & 1;
    const int ar = i0 + rh * 32;
    const int bc = j0 + ch * 64;
    const int lrow = lane & 15;
    const int kgrp = (lane >> 4) * 8;

    __shared__ unsigned short lds_c[64][CPAD];

    f32x4 acc[2][4];
#pragma unroll
    for (int a = 0; a < 2; ++a)
#pragma unroll
        for (int c = 0; c < 4; ++c) acc[a][c] = (f32x4){0.f, 0.f, 0.f, 0.f};

    short8 ah[2][4], bh[4][4];
#pragma unroll
    for (int kc = 0; kc < 4; ++kc) {
#pragma unroll
        for (int f = 0; f < 2; ++f)
            ah[f][kc] = *reinterpret_cast<const short8*>(
                P.Ah + (size_t)(ar + f * 16 + lrow) * 128 + kc * 32 + kgrp);
#pragma unroll
        for (int f = 0; f < 4; ++f)
            bh[f][kc] = *reinterpret_cast<const short8*>(
                P.Bh + (size_t)(bc + f * 16 + lrow) * 128 + kc * 32 + kgrp);
    }
#pragma unroll
    for (int kc = 0; kc < 4; ++kc)
#pragma unroll
        for (int fi = 0; fi < 2; ++fi)
#pragma unroll
            for (int fj = 0; fj < 4; ++fj)
                acc[fi][fj] = __builtin_amdgcn_mfma_f32_16x16x32_bf16(
                    bh[fj][kc], ah[fi][kc], acc[fi][fj], 0, 0, 0);

    // C^T frag -> LDS stage (C-row = lane&15, C-col = (lane>>4)*4 + e)
    const int rloc = lane & 15, cloc = (lane >> 4) * 4;
#pragma unroll
    for (int fi = 0; fi < 2; ++fi) {
        int lr = rh * 32 + fi * 16 + rloc;
        float ha = P.hna[i0 + lr];
#pragma unroll
        for (int fj = 0; fj < 4; ++fj) {
            int lc = ch * 64 + fj * 16 + cloc;
            f32x4 hb = *reinterpret_cast<const f32x4*>(P.hnb + j0 + lc);
            u16x4 v;
#pragma unroll
            for (int e = 0; e < 4; ++e)
                v[e] = f2h(fmaxf(ha + hb[e] - acc[fi][fj][e], 0.f));
            *reinterpret_cast<u16x4*>(&lds_c[lr][lc]) = v;
        }
    }
    __syncthreads();
    // C store: thread t -> row t>>2, 32-col quarter t&3 (row-contiguous)
    {
        const int row = threadIdx.x >> 2, q = threadIdx.x & 3;
        const unsigned short* srcp = &lds_c[row][q * 32];
        unsigned short* dstp = P.C + (size_t)(i0 + row) * P.ldc + j0 + q * 32;
#pragma unroll
        for (int k = 0; k < 4; ++k)
            *reinterpret_cast<u16x8*>(dstp + 8 * k) =
                *reinterpret_cast<const u16x8*>(srcp + 8 * k);
    }
    // CT store: thread t -> CT row (orig col) t>>1, 32-row half t&1
    if (P.CT) {
        const int tr = threadIdx.x >> 1, half = threadIdx.x & 1;
        unsigned short* dstp = P.CT + (size_t)(j0 + tr) * P.ldct + i0 + half * 32;
#pragma unroll
        for (int k = 0; k < 4; ++k) {
            u16x8 v;
#pragma unroll
            for (int e = 0; e < 8; ++e)
                v[e] = lds_c[half * 32 + k * 8 + e][tr];
            *reinterpret_cast<u16x8*>(dstp + 8 * k) = v;
        }
    }
}

// ------------------------------ round kernel -------------------------------
// Uniform row-only softmin: 8 rows/block, thread t owns W/256 contiguous
// cols. Per row: v = Win[j] - C[row][j]*ie2, two-pass LSE (1 exp2/elem);
// 256-partial LDS reduce; finalize vnew + next-round weight wout.

struct RT7 {
    const unsigned short* C;      // [rows][W] fp16
    const float* Win;             // W-wide weights
    const float* fold; const float* logself;
    float* vout; float* wout;
    int blk0; int wide;           // wide: 0 -> W=2048, 1 -> W=4096
};
struct R7Args {
    RT7 t[6];
    float ie2, epsln2, ie2n, alpha, beta;
};

__global__ __launch_bounds__(256, 8)
void k_round7(R7Args A)
{
    __shared__ float lmS[8][256];
    __shared__ float lsS[8][256];
    const int b = blockIdx.x;
    const int tid = threadIdx.x;
    const float nie2 = -A.ie2;

    int ti = 5;
    if      (b < A.t[1].blk0) ti = 0;
    else if (b < A.t[2].blk0) ti = 1;
    else if (b < A.t[3].blk0) ti = 2;
    else if (b < A.t[4].blk0) ti = 3;
    else if (b < A.t[5].blk0) ti = 4;
    RT7 T = A.t[ti];
    const int row0 = (b - T.blk0) * 8;

    if (!T.wide) {
        const int c0 = tid * 8;
        float wb[8];
#pragma unroll
        for (int e = 0; e < 8; ++e) wb[e] = T.Win[c0 + e];
#pragma unroll
        for (int r = 0; r < 8; ++r) {
            u16x8 c = *reinterpret_cast<const u16x8*>(T.C + (size_t)(row0 + r) * 2048 + c0);
            float v[8];
#pragma unroll
            for (int e = 0; e < 8; ++e) v[e] = fmaf(h2f(c[e]), nie2, wb[e]);
            float M8 = max8(v);
            float s8 = 0.f;
#pragma unroll
            for (int e = 0; e < 8; ++e) s8 += exp2fast(v[e] - M8);
            lmS[r][tid] = M8; lsS[r][tid] = s8;
        }
    } else {
        const int c0 = tid * 16;
        float wb[16];
#pragma unroll
        for (int e = 0; e < 16; ++e) wb[e] = T.Win[c0 + e];
#pragma unroll
        for (int r = 0; r < 8; ++r) {
            const unsigned short* Cr = T.C + (size_t)(row0 + r) * 4096 + c0;
            u16x8 ca = *reinterpret_cast<const u16x8*>(Cr);
            u16x8 cb = *reinterpret_cast<const u16x8*>(Cr + 8);
            float v[16];
#pragma unroll
            for (int e = 0; e < 8; ++e) {
                v[e]     = fmaf(h2f(ca[e]), nie2, wb[e]);
                v[8 + e] = fmaf(h2f(cb[e]), nie2, wb[8 + e]);
            }
            float M = fmaxf(max8(v), max8(v + 8));
            float s = 0.f;
#pragma unroll
            for (int e = 0; e < 16; ++e) s += exp2fast(v[e] - M);
            lmS[r][tid] = M; lsS[r][tid] = s;
        }
    }
    __syncthreads();
    {
        const int row = tid >> 5, g = tid & 31;
        float m = lmS[row][g], s = lsS[row][g];
#pragma unroll
        for (int k = 1; k < 8; ++k)
            lse2_merge(m, s, lmS[row][g + 32 * k], lsS[row][g + 32 * k]);
#pragma unroll
        for (int o = 1; o < 32; o <<= 1) {
            float mo = __shfl_xor(m, o), so = __shfl_xor(s, o);
            lse2_merge(m, s, mo, so);
        }
        if (g == 0) {
            int rr = row0 + row;
            float val  = -A.epsln2 * (m + __log2f(s));
            float vnew = A.alpha * T.fold[rr] + A.beta * val;
            T.vout[rr] = vnew;
            T.wout[rr] = fmaf(vnew, A.ie2n, T.logself[rr]);
        }
    }
}

// ------------------------------ final reduce -------------------------------
__global__ __launch_bounds__(1024)
void k_final(const float* __restrict__ h, const float* __restrict__ hi,
             const float* __restrict__ hj,
             const float* __restrict__ f1f, const float* __restrict__ f2f,
             const float* __restrict__ g1f, const float* __restrict__ gb1f,
             const float* __restrict__ g2f, const float* __restrict__ gb2f,
             int N, int M, float* __restrict__ out)
{
    float acc = 0.f;
    for (int i = threadIdx.x; i < N; i += 1024)
        acc += h[i] * (f2f[i] - f1f[i]);
    for (int j = threadIdx.x; j < M; j += 1024)
        acc += hj[j] * (g2f[j] - gb2f[j]) - hi[j] * (g1f[j] - gb1f[j]);
#pragma unroll
    for (int o = 32; o; o >>= 1) acc += __shfl_xor(acc, o);
    __shared__ float red[16];
    const int lane = threadIdx.x & 63, w = threadIdx.x >> 6;
    if (lane == 0) red[w] = acc;
    __syncthreads();
    if (threadIdx.x == 0) {
        float t = 0.f;
        for (int q = 0; q < 16; ++q) t += red[q];
        out[0] = 1.f / (1.f + expf(-t));   // SCALING_FACTOR = 1
    }
}

// ------------------------------ orchestration ------------------------------

extern "C" void kernel_launch(void* const* d_in, const int* in_sizes, int n_in,
                              void* d_out, int out_size, void* d_ws, size_t ws_size,
                              hipStream_t stream)
{
    const float* d  = (const float*)d_in[0];
    const float* si = (const float*)d_in[1];
    const float* sj = (const float*)d_in[2];
    const float* h  = (const float*)d_in[3];
    const float* hi = (const float*)d_in[4];
    const float* hj = (const float*)d_in[5];
    const float* W  = (const float*)d_in[6];
    float* out = (float*)d_out;

    const int N = 4096, M = 2048;
    (void)in_sizes; (void)n_in; (void)out_size; (void)ws_size;

    float* ws = (float*)d_ws;
    size_t off = 0;
    auto alloc = [&](size_t n) { float* p = ws + off; off += (n + 63) & ~(size_t)63; return p; };

    float* WT    = alloc(128 * 128);
    float* lg2   = alloc(8192);
    float* hnAll = alloc(8192);
    unsigned short* thAll = (unsigned short*)alloc(8192 * 128 / 2);
    float* f1[2]  = { alloc(N), alloc(N) };
    float* f2[2]  = { alloc(N), alloc(N) };
    float* g1[2]  = { alloc(M), alloc(M) };
    float* g2[2]  = { alloc(M), alloc(M) };
    float* gb1[2] = { alloc(M), alloc(M) };
    float* gb2[2] = { alloc(M), alloc(M) };
    float* WA1[2] = { alloc(N), alloc(N) };
    float* WA2[2] = { alloc(N), alloc(N) };
    float* WB1[2] = { alloc(M), alloc(M) };
    float* WB2[2] = { alloc(M), alloc(M) };
    float* WY1[2] = { alloc(M), alloc(M) };
    float* WY2[2] = { alloc(M), alloc(M) };
    float* f1f = alloc(N); float* f2f = alloc(N);
    float* g1f = alloc(M); float* g2f = alloc(M);
    float* gb1f = alloc(M); float* gb2f = alloc(M);
    unsigned short* C1  = (unsigned short*)alloc((size_t)N * M / 2);
    unsigned short* C2  = (unsigned short*)alloc((size_t)N * M / 2);
    unsigned short* CT1 = (unsigned short*)alloc((size_t)M * N / 2);
    unsigned short* CT2 = (unsigned short*)alloc((size_t)M * N / 2);
    unsigned short* Cy1 = (unsigned short*)alloc((size_t)M * M / 2);
    unsigned short* Cy2 = (unsigned short*)alloc((size_t)M * M / 2);

    float* la2  = lg2;
    float* lbi2 = lg2 + 4096;
    float* lbj2 = lg2 + 6144;
    const float* hnx = hnAll;
    const float* hni = hnAll + 4096;
    const float* hnj = hnAll + 6144;
    const unsigned short* tdh  = thAll;
    const unsigned short* tsih = thAll + (size_t)4096 * 128;
    const unsigned short* tsjh = thAll + (size_t)6144 * 128;

    // ---- setup ----
    k_setup<<<96, 256, 0, stream>>>(W, WT, h, hi, hj, lg2);
    k_transform_all<<<1024, 128, 0, stream>>>(d, si, sj, WT, thAll, hnAll);

    // ---- cost matrices (+ CT for xy): ONE launch, 2560 blocks ----
    CostQuad Q;
    Q.p[0] = { tdh,  tsih, hnx, hni, C1,  CT1,     M, N,    0, 16 };
    Q.p[1] = { tdh,  tsjh, hnx, hnj, C2,  CT2,     M, N, 1024, 16 };
    Q.p[2] = { tsih, tsih, hni, hni, Cy1, nullptr, M, 0, 2048, 16 };
    Q.p[3] = { tsjh, tsjh, hnj, hnj, Cy2, nullptr, M, 0, 2304, 16 };
    k_cost_mfma<<<2560, 256, 0, stream>>>(Q);

    // ---- eps schedule ----
    double epsl[16]; int ne = 0;
    for (double sg = 32.0; sg > 0.05; sg *= 0.5) epsl[ne++] = sg * sg;
    epsl[ne++] = 0.05 * 0.05;   // ne == 11

    for (int r = 0; r <= ne + 1; ++r) {
        const bool init = (r == 0), fin = (r == ne + 1);
        const double eps  = init ? epsl[0] : (fin ? epsl[ne - 1] : epsl[r - 1]);
        const double epsn = (r + 1 <= ne) ? epsl[r] : epsl[ne - 1];
        const int in = init ? 0 : (r - 1) & 1;
        const int o  = r & 1;

        R7Args A;
        A.ie2    = (float)(LOG2E / eps);
        A.epsln2 = (float)(eps * LN2);
        A.ie2n   = (float)(LOG2E / epsn);
        A.alpha  = (init || fin) ? 0.0f : 0.5f;
        A.beta   = (init || fin) ? 1.0f : 0.5f;
        // f updates over C (narrow), g updates over CT (wide), gb over Cy
        A.t[0] = { C1,  init ? lbi2 : WB1[in], f1[in],  la2,
                   fin ? f1f  : f1[o],  WA1[o],    0, 0 };
        A.t[1] = { C2,  init ? lbj2 : WB2[in], f2[in],  la2,
                   fin ? f2f  : f2[o],  WA2[o],  512, 0 };
        A.t[2] = { CT1, init ? la2  : WA1[in], g1[in],  lbi2,
                   fin ? g1f  : g1[o],  WB1[o], 1024, 1 };
        A.t[3] = { CT2, init ? la2  : WA2[in], g2[in],  lbj2,
                   fin ? g2f  : g2[o],  WB2[o], 1280, 1 };
        A.t[4] = { Cy1, init ? lbi2 : WY1[in], gb1[in], lbi2,
                   fin ? gb1f : gb1[o], WY1[o], 1536, 0 };
        A.t[5] = { Cy2, init ? lbj2 : WY2[in], gb2[in], lbj2,
                   fin ? gb2f : gb2[o], WY2[o], 1792, 0 };
        k_round7<<<2048, 256, 0, stream>>>(A);
    }

    k_final<<<1, 1024, 0, stream>>>(h, hi, hj, f1f, f2f, g1f, gb1f, g2f, gb2f, N, M, out);
}